// Round 9
// baseline (286.649 us; speedup 1.0000x reference)
//
#include <hip/hip_runtime.h>

// SplineCNN on MI355X.
// Sparse edge extraction (adj ~6% dense, basis shared across layers);
// per-layer: split-bf16 MFMA GEMM [B*N,3K]x[3K,640] -> bf16 hw (+fp32 root) ->
// sparse aggregate (+root+bias+relu, emits next layer's split-bf16 input).
// Aggregate (r9): half-wave per edge — lanes 0-31 edge e, lanes 32-63 edge e+1,
// each lane loads a DWORD (2 adjacent bf16 f-columns) -> half the vmem
// instructions of r8 at identical bytes/lines (tests the L1-miss-rate ceiling).
// Halves combined via __shfl_xor(32). XCD-swizzled grid, LDS-staged edge lists.
// Layer-2 aggregate fuses global max-pool via uint-bitcast atomicMax (relu >= 0).
// Setup (convx + 3x packw + zerog) fused into one dispatch.

#define B_   32
#define N_   512
#define F_   64
#define CAP  128          // max neighbors per node (mean ~31, 128 is >>6 sigma)
#define NCOL 640          // 9*F (spline kernels) + F (root)
#define HWC  576          // 9*F bf16 spline cols per row

typedef short bf16x8 __attribute__((ext_vector_type(8)));
typedef float f32x4  __attribute__((ext_vector_type(4)));

__device__ __forceinline__ unsigned short to_bf16_rne(float v) {
  unsigned u = __float_as_uint(v);
  unsigned r = u + 0x7fffu + ((u >> 16) & 1u);
  return (unsigned short)(r >> 16);
}
__device__ __forceinline__ float bf16_to_f(unsigned short h) {
  return __uint_as_float(((unsigned)h) << 16);
}
__device__ __forceinline__ float lo_bf(unsigned u) { return __uint_as_float(u << 16); }
__device__ __forceinline__ float hi_bf(unsigned u) { return __uint_as_float(u & 0xffff0000u); }

// ---------------- preprocess: edge lists + factored spline basis ----------------
// edge record: float4 { bitcast(m*288 + k0c*32), fx, fy, 1.0 }  (DWORD base into
// hwbf[b] dword view; w=1 marks valid; zero records give all-zero tap weights)
__global__ __launch_bounds__(512) void preprocess_kernel(
    const float* __restrict__ adj, const float* __restrict__ coord,
    float4* __restrict__ edge, int* __restrict__ cnt_out,
    float* __restrict__ deginv_out) {
  int row = blockIdx.x;          // b*N + n
  int b = row >> 9;
  int tid = threadIdx.x;         // == m (within batch)
  int lane = tid & 63, wave = tid >> 6;
  __shared__ int wcnt[8];
  float a = adj[(size_t)row * N_ + tid];
  bool flag = (a != 0.0f);
  unsigned long long ball = __ballot(flag);
  if (lane == 0) wcnt[wave] = __popcll(ball);
  __syncthreads();
  int woff = 0, total = 0;
  #pragma unroll
  for (int i = 0; i < 8; ++i) { int c = wcnt[i]; if (i < wave) woff += c; total += c; }
  if (flag) {
    int pos = woff + __popcll(ball & ((1ULL << lane) - 1));
    if (pos < CAP) {
      int m = tid;
      float cxn = coord[(size_t)row * 2 + 0];
      float cyn = coord[(size_t)row * 2 + 1];
      float cxm = coord[(size_t)(b * N_ + m) * 2 + 0];
      float cym = coord[(size_t)(b * N_ + m) * 2 + 1];
      float vx = (cxm - cxn + 1.0f) * 0.5f * 2.0f;
      float vy = (cym - cyn + 1.0f) * 0.5f * 2.0f;
      float i0x = fminf(fmaxf(floorf(vx), 0.0f), 1.0f);
      float i0y = fminf(fmaxf(floorf(vy), 0.0f), 1.0f);
      float fx = vx - i0x, fy = vy - i0y;
      int k0c = (int)i0x * 3 + (int)i0y;
      int ebase = m * 288 + k0c * 32;   // dword index into hwbf[b]
      edge[(size_t)row * CAP + pos] =
          make_float4(__int_as_float(ebase), fx, fy, 1.0f);
    }
  }
  if (tid == 0) {
    cnt_out[row] = total > CAP ? CAP : total;
    deginv_out[row] = 1.0f / (float)(total > 0 ? total : 1);
  }
}

// ---------------- fused setup: convx + packw(x3) + zerog ----------------
__device__ __forceinline__ void packw_body(
    const float* __restrict__ w, const float* __restrict__ root,
    int cin, unsigned short* __restrict__ wt, int idx) {
  int total = NCOL * cin;
  if (idx >= total) return;
  int n = idx / cin, k = idx - n * cin;
  int kk = n >> 6, f = n & 63;
  float v = (kk < 9) ? w[((size_t)kk * cin + k) * F_ + f]
                     : root[(size_t)k * F_ + f];
  unsigned short hi = to_bf16_rne(v);
  unsigned short lo = to_bf16_rne(v - bf16_to_f(hi));
  size_t base = (size_t)n * (3 * cin);
  wt[base + k] = hi;
  wt[base + cin + k] = hi;
  wt[base + 2 * cin + k] = lo;
}

__global__ __launch_bounds__(256) void setup_kernel(
    const float* __restrict__ x,
    const float* __restrict__ w0, const float* __restrict__ root0,
    const float* __restrict__ w1, const float* __restrict__ root1,
    const float* __restrict__ w2, const float* __restrict__ root2,
    unsigned short* __restrict__ abf0,
    unsigned short* __restrict__ wt0, unsigned short* __restrict__ wt1,
    unsigned short* __restrict__ wt2, unsigned int* __restrict__ gmax) {
  int blk = blockIdx.x, tid = threadIdx.x;
  if (blk < 8192) {                        // convx: R*128 elements
    int idx = blk * 256 + tid;
    int row = idx >> 7, k = idx & 127;
    float v = x[idx];
    unsigned short hi = to_bf16_rne(v);
    unsigned short lo = to_bf16_rne(v - bf16_to_f(hi));
    size_t base = (size_t)row * 384;
    abf0[base + k] = hi;
    abf0[base + 128 + k] = lo;
    abf0[base + 256 + k] = hi;
  } else if (blk < 8512) {                 // packw0: 640*128
    packw_body(w0, root0, 128, wt0, (blk - 8192) * 256 + tid);
  } else if (blk < 8672) {                 // packw1: 640*64
    packw_body(w1, root1, 64, wt1, (blk - 8512) * 256 + tid);
  } else if (blk < 8832) {                 // packw2: 640*64
    packw_body(w2, root2, 64, wt2, (blk - 8672) * 256 + tid);
  } else {                                 // zerog: 2048
    int idx = (blk - 8832) * 256 + tid;
    if (idx < B_ * F_) gmax[idx] = 0u;
  }
}

// ---------------- split-bf16 MFMA GEMM -> bf16 hw + fp32 root ----------------
// 128x128 tile, 256 threads = 4 waves (2x2 of 64x64), 16x16x32 bf16 MFMA, BK=64.
// LDS rows padded +8 bf16 (stride 144B -> conflict-free b128 frag reads).
// Epilogue: kk=(bn+nw)>>6 wave-uniform; spline cols -> bf16 hwbf (contiguous-lane
// ushort stores), root block -> fp32 hwroot.
#define BK 64
#define LDK (BK + 8)
__global__ __launch_bounds__(256) void gemm_mfma_kernel(
    const unsigned short* __restrict__ A,   // [M][KP]
    const unsigned short* __restrict__ Wt,  // [640][KP]  (W^T, n-major)
    unsigned short* __restrict__ hwbf,      // [M][576] bf16
    float* __restrict__ hwroot,             // [M][64] fp32
    int KP) {
  __shared__ unsigned short As[128 * LDK];
  __shared__ unsigned short Ws[128 * LDK];
  int bm = blockIdx.x * 128;
  int bn = blockIdx.y * 128;
  int tid = threadIdx.x;
  int wave = tid >> 6, lane = tid & 63;
  int mw = (wave & 1) * 64, nw = (wave >> 1) * 64;
  int lr = lane & 15, quad = lane >> 4;

  f32x4 acc[4][4] = {};
  for (int k0 = 0; k0 < KP; k0 += BK) {
    #pragma unroll
    for (int i = 0; i < 4; ++i) {
      int c = tid + i * 256;            // 0..1023 chunks of 16B
      int row = c >> 3, ck = (c & 7) * 8;
      *(float4*)&As[row * LDK + ck] =
          *(const float4*)&A[(size_t)(bm + row) * KP + k0 + ck];
      *(float4*)&Ws[row * LDK + ck] =
          *(const float4*)&Wt[(size_t)(bn + row) * KP + k0 + ck];
    }
    __syncthreads();
    #pragma unroll
    for (int kk = 0; kk < BK; kk += 32) {
      bf16x8 af[4], bf[4];
      #pragma unroll
      for (int i = 0; i < 4; ++i)
        af[i] = *(const bf16x8*)&As[(mw + 16 * i + lr) * LDK + kk + quad * 8];
      #pragma unroll
      for (int j = 0; j < 4; ++j)
        bf[j] = *(const bf16x8*)&Ws[(nw + 16 * j + lr) * LDK + kk + quad * 8];
      #pragma unroll
      for (int i = 0; i < 4; ++i)
        #pragma unroll
        for (int j = 0; j < 4; ++j)
          acc[i][j] = __builtin_amdgcn_mfma_f32_16x16x32_bf16(af[i], bf[j], acc[i][j], 0, 0, 0);
    }
    __syncthreads();
  }
  // epilogue: C/D layout col=lane&15, row=quad*4+reg (m89-verified).
  int kku = (bn + nw) >> 6;
  if (kku < 9) {
    #pragma unroll
    for (int i = 0; i < 4; ++i)
      #pragma unroll
      for (int j = 0; j < 4; ++j)
        #pragma unroll
        for (int r = 0; r < 4; ++r) {
          int m = bm + mw + 16 * i + quad * 4 + r;
          int n = bn + nw + 16 * j + lr;            // 64*kku .. 64*kku+63
          hwbf[(size_t)m * HWC + n] = to_bf16_rne(acc[i][j][r]);
        }
  } else {
    #pragma unroll
    for (int i = 0; i < 4; ++i)
      #pragma unroll
      for (int j = 0; j < 4; ++j)
        #pragma unroll
        for (int r = 0; r < 4; ++r) {
          int m = bm + mw + 16 * i + quad * 4 + r;
          int f = 16 * j + lr;
          hwroot[(size_t)m * F_ + f] = acc[i][j][r];
        }
  }
}

// ---------------- sparse aggregate (bf16 hw, half-wave per edge) ----------------
// 256 threads = 4 waves, one row per wave. XCD-swizzled (blockIdx&7 = XCD).
// Lanes 0-31 process edges e0..e0+3, lanes 32-63 edges e0+4..e0+7; each lane
// loads a dword = 2 adjacent bf16 f-cols (dense 128B per half per tap).
// 16 dword gathers per 8 edges (vs 32 ushort) at identical bytes/lines.
__global__ __launch_bounds__(256) void aggregate_kernel(
    const unsigned int* __restrict__ hw32,   // dword view of hwbf [M][288]
    const float* __restrict__ hwroot,
    const float4* __restrict__ edge,
    const int* __restrict__ cnt, const float* __restrict__ deginv,
    const float* __restrict__ bias,
    unsigned short* __restrict__ aout,
    unsigned int* __restrict__ gmax) {
  __shared__ float4 esh[4][CAP];
  int wave = threadIdx.x >> 6;
  int lane = threadIdx.x & 63;
  int half = lane >> 5;          // which edge group
  int i = lane & 31;             // f-pair index: f = 2i, 2i+1
  int xcd = blockIdx.x & 7;
  int j = blockIdx.x >> 3;
  int b = xcd * 4 + (j >> 7);
  int row = b * N_ + ((j & 127) << 2) + wave;
  int c = cnt[row];
  int cpad = (c + 7) & ~7;
  size_t ebase = (size_t)row * CAP;
  for (int t = lane; t < cpad; t += 64)
    esh[wave][t] = (t < c) ? edge[ebase + t] : make_float4(0.f, 0.f, 0.f, 0.f);
  __syncthreads();

  const unsigned int* pb = hw32 + (size_t)b * (N_ * 288) + i;
  float accE[2] = {0.f, 0.f}, accO[2] = {0.f, 0.f};
  for (int e0 = 0; e0 < cpad; e0 += 8) {
    int off[4];
    float w00[4], w01[4], w10[4], w11[4];
    #pragma unroll
    for (int q = 0; q < 4; ++q) {
      float4 er = esh[wave][e0 + 4 * half + q];
      off[q] = __float_as_int(er.x);
      float bx1 = er.y, by1 = er.z, v = er.w;
      float bx0 = v - bx1, by0 = v - by1;
      w00[q] = bx0 * by0; w01[q] = bx0 * by1;
      w10[q] = bx1 * by0; w11[q] = bx1 * by1;
    }
    unsigned u0[4], u1[4], u2[4], u3[4];
    #pragma unroll
    for (int q = 0; q < 4; ++q) {
      const unsigned int* p = pb + off[q];
      u0[q] = p[0]; u1[q] = p[32]; u2[q] = p[96]; u3[q] = p[128];
    }
    #pragma unroll
    for (int q = 0; q < 4; ++q) {
      accE[q & 1] += w00[q] * lo_bf(u0[q]) + w01[q] * lo_bf(u1[q])
                   + w10[q] * lo_bf(u2[q]) + w11[q] * lo_bf(u3[q]);
      accO[q & 1] += w00[q] * hi_bf(u0[q]) + w01[q] * hi_bf(u1[q])
                   + w10[q] * hi_bf(u2[q]) + w11[q] * hi_bf(u3[q]);
    }
  }
  float aE = accE[0] + accE[1];
  float aO = accO[0] + accO[1];
  aE += __shfl_xor(aE, 32, 64);
  aO += __shfl_xor(aO, 32, 64);
  if (half == 0) {
    float di = deginv[row];
    float2 rv = *(const float2*)&hwroot[(size_t)row * F_ + 2 * i];
    float2 bs = *(const float2*)&bias[2 * i];
    float vE = fmaxf(aE * di + rv.x + bs.x, 0.0f);
    float vO = fmaxf(aO * di + rv.y + bs.y, 0.0f);
    if (aout) {
      unsigned hiE = to_bf16_rne(vE), loE = to_bf16_rne(vE - bf16_to_f((unsigned short)hiE));
      unsigned hiO = to_bf16_rne(vO), loO = to_bf16_rne(vO - bf16_to_f((unsigned short)hiO));
      unsigned int* a32 = (unsigned int*)aout;
      size_t base = (size_t)row * 96;       // dword base of [row][192] ushorts
      a32[base + i]      = hiE | (hiO << 16);
      a32[base + 32 + i] = loE | (loO << 16);
      a32[base + 64 + i] = hiE | (hiO << 16);
    }
    if (gmax) {
      // relu output >= 0 -> IEEE bits monotone under unsigned compare
      atomicMax(&gmax[b * F_ + 2 * i],     __float_as_uint(vE));
      atomicMax(&gmax[b * F_ + 2 * i + 1], __float_as_uint(vO));
    }
  }
}

// ---------------- FC from pooled features ----------------
__global__ __launch_bounds__(64) void fc_kernel(
    const float* __restrict__ g, const float* __restrict__ fcw,
    const float* __restrict__ fcb, float* __restrict__ out) {
  int b = blockIdx.x;
  int f = threadIdx.x;
  __shared__ float gs[64];
  gs[f] = g[b * F_ + f];
  __syncthreads();
  if (f < 10) {
    float s = fcb[f];
    #pragma unroll
    for (int c = 0; c < 64; ++c) s += gs[c] * fcw[c * 10 + f];
    out[b * 10 + f] = s;
  }
}

extern "C" void kernel_launch(void* const* d_in, const int* in_sizes, int n_in,
                              void* d_out, int out_size, void* d_ws, size_t ws_size,
                              hipStream_t stream) {
  const float* x     = (const float*)d_in[0];
  const float* coord = (const float*)d_in[1];
  const float* adj   = (const float*)d_in[2];
  const float* w0    = (const float*)d_in[3];
  const float* root0 = (const float*)d_in[4];
  const float* b0    = (const float*)d_in[5];
  const float* w1    = (const float*)d_in[6];
  const float* root1 = (const float*)d_in[7];
  const float* b1    = (const float*)d_in[8];
  const float* w2    = (const float*)d_in[9];
  const float* root2 = (const float*)d_in[10];
  const float* b2    = (const float*)d_in[11];
  const float* fcw   = (const float*)d_in[12];
  const float* fcb   = (const float*)d_in[13];
  float* out = (float*)d_out;

  char* ws = (char*)d_ws;
  size_t off = 0;
  auto alloc = [&](size_t bytes) {
    void* p = ws + off;
    off = (off + bytes + 255) & ~(size_t)255;
    return p;
  };
  const int R = B_ * N_;  // 16384
  float4* edge    = (float4*)alloc((size_t)R * CAP * 16);
  int*    cnt     = (int*)   alloc((size_t)R * 4);
  float*  deginv  = (float*) alloc((size_t)R * 4);
  unsigned short* abf0 = (unsigned short*)alloc((size_t)R * 384 * 2);
  unsigned short* abfN = (unsigned short*)alloc((size_t)R * 192 * 2);
  unsigned short* wt0  = (unsigned short*)alloc((size_t)NCOL * 384 * 2);
  unsigned short* wt1  = (unsigned short*)alloc((size_t)NCOL * 192 * 2);
  unsigned short* wt2  = (unsigned short*)alloc((size_t)NCOL * 192 * 2);
  unsigned short* hwbf = (unsigned short*)alloc((size_t)R * HWC * 2);
  float*  hwroot  = (float*) alloc((size_t)R * F_ * 4);
  unsigned int* gmax = (unsigned int*)alloc((size_t)B_ * F_ * 4);

  preprocess_kernel<<<R, 512, 0, stream>>>(adj, coord, edge, cnt, deginv);
  setup_kernel<<<8840, 256, 0, stream>>>(x, w0, root0, w1, root1, w2, root2,
                                         abf0, wt0, wt1, wt2, gmax);

  // layer 0 (Cin=128, KP=384)
  gemm_mfma_kernel<<<dim3(R / 128, NCOL / 128), 256, 0, stream>>>(abf0, wt0, hwbf, hwroot, 384);
  aggregate_kernel<<<R / 4, 256, 0, stream>>>((const unsigned int*)hwbf, hwroot, edge, cnt, deginv, b0, abfN, nullptr);

  // layer 1 (Cin=64, KP=192)
  gemm_mfma_kernel<<<dim3(R / 128, NCOL / 128), 256, 0, stream>>>(abfN, wt1, hwbf, hwroot, 192);
  aggregate_kernel<<<R / 4, 256, 0, stream>>>((const unsigned int*)hwbf, hwroot, edge, cnt, deginv, b1, abfN, nullptr);

  // layer 2 (Cin=64, KP=192) — fused max-pool
  gemm_mfma_kernel<<<dim3(R / 128, NCOL / 128), 256, 0, stream>>>(abfN, wt2, hwbf, hwroot, 192);
  aggregate_kernel<<<R / 4, 256, 0, stream>>>((const unsigned int*)hwbf, hwroot, edge, cnt, deginv, b2, nullptr, gmax);

  fc_kernel<<<B_, 64, 0, stream>>>((const float*)gmax, fcw, fcb, out);
}

// Round 10
// 279.717 us; speedup vs baseline: 1.0248x; 1.0248x over previous
//
#include <hip/hip_runtime.h>

// SplineCNN on MI355X.
// Sparse edge extraction (adj ~6% dense, basis shared across layers);
// per-layer: split-bf16 MFMA GEMM [B*N,3K]x[3K,640] -> bf16 hw (+fp32 root) ->
// sparse aggregate (+root+bias+relu, emits next layer's split-bf16 input).
// Aggregate (r10): one row per wave, full-wave (64 f) ushort taps like r8 (best),
// plus (a) readfirstlane -> SGPR edge base: taps are global_load_ushort with
// immediate offsets off a scalar base (kills per-lane 64-bit addr chains);
// (b) explicit ping-pong prefetch of 4-edge groups: next group's 16 loads are
// in flight while current group's FMAs run (partial vmcnt instead of drain).
// XCD-swizzled grid (L2 locality), LDS-staged edge lists.
// Layer-2 aggregate fuses global max-pool via uint-bitcast atomicMax (relu >= 0).
// Setup (convx + 3x packw + zerog) fused into one dispatch.

#define B_   32
#define N_   512
#define F_   64
#define CAP  128          // max neighbors per node (mean ~31, 128 is >>6 sigma)
#define NCOL 640          // 9*F (spline kernels) + F (root)
#define HWC  576          // 9*F bf16 spline cols per row

typedef short bf16x8 __attribute__((ext_vector_type(8)));
typedef float f32x4  __attribute__((ext_vector_type(4)));

__device__ __forceinline__ unsigned short to_bf16_rne(float v) {
  unsigned u = __float_as_uint(v);
  unsigned r = u + 0x7fffu + ((u >> 16) & 1u);
  return (unsigned short)(r >> 16);
}
__device__ __forceinline__ float bf16_to_f(unsigned short h) {
  return __uint_as_float(((unsigned)h) << 16);
}

// ---------------- preprocess: edge lists + factored spline basis ----------------
// edge record: float4 { bitcast(m*576 + k0c*64), fx, fy, 1.0 }  (ushort base into
// hwbf[b]; w=1 marks valid; zero records give all-zero tap weights and base 0)
__global__ __launch_bounds__(512) void preprocess_kernel(
    const float* __restrict__ adj, const float* __restrict__ coord,
    float4* __restrict__ edge, int* __restrict__ cnt_out,
    float* __restrict__ deginv_out) {
  int row = blockIdx.x;          // b*N + n
  int b = row >> 9;
  int tid = threadIdx.x;         // == m (within batch)
  int lane = tid & 63, wave = tid >> 6;
  __shared__ int wcnt[8];
  float a = adj[(size_t)row * N_ + tid];
  bool flag = (a != 0.0f);
  unsigned long long ball = __ballot(flag);
  if (lane == 0) wcnt[wave] = __popcll(ball);
  __syncthreads();
  int woff = 0, total = 0;
  #pragma unroll
  for (int i = 0; i < 8; ++i) { int c = wcnt[i]; if (i < wave) woff += c; total += c; }
  if (flag) {
    int pos = woff + __popcll(ball & ((1ULL << lane) - 1));
    if (pos < CAP) {
      int m = tid;
      float cxn = coord[(size_t)row * 2 + 0];
      float cyn = coord[(size_t)row * 2 + 1];
      float cxm = coord[(size_t)(b * N_ + m) * 2 + 0];
      float cym = coord[(size_t)(b * N_ + m) * 2 + 1];
      float vx = (cxm - cxn + 1.0f) * 0.5f * 2.0f;
      float vy = (cym - cyn + 1.0f) * 0.5f * 2.0f;
      float i0x = fminf(fmaxf(floorf(vx), 0.0f), 1.0f);
      float i0y = fminf(fmaxf(floorf(vy), 0.0f), 1.0f);
      float fx = vx - i0x, fy = vy - i0y;
      int k0c = (int)i0x * 3 + (int)i0y;
      int ebase = m * HWC + k0c * F_;   // ushort index into hwbf[b]
      edge[(size_t)row * CAP + pos] =
          make_float4(__int_as_float(ebase), fx, fy, 1.0f);
    }
  }
  if (tid == 0) {
    cnt_out[row] = total > CAP ? CAP : total;
    deginv_out[row] = 1.0f / (float)(total > 0 ? total : 1);
  }
}

// ---------------- fused setup: convx + packw(x3) + zerog ----------------
__device__ __forceinline__ void packw_body(
    const float* __restrict__ w, const float* __restrict__ root,
    int cin, unsigned short* __restrict__ wt, int idx) {
  int total = NCOL * cin;
  if (idx >= total) return;
  int n = idx / cin, k = idx - n * cin;
  int kk = n >> 6, f = n & 63;
  float v = (kk < 9) ? w[((size_t)kk * cin + k) * F_ + f]
                     : root[(size_t)k * F_ + f];
  unsigned short hi = to_bf16_rne(v);
  unsigned short lo = to_bf16_rne(v - bf16_to_f(hi));
  size_t base = (size_t)n * (3 * cin);
  wt[base + k] = hi;
  wt[base + cin + k] = hi;
  wt[base + 2 * cin + k] = lo;
}

__global__ __launch_bounds__(256) void setup_kernel(
    const float* __restrict__ x,
    const float* __restrict__ w0, const float* __restrict__ root0,
    const float* __restrict__ w1, const float* __restrict__ root1,
    const float* __restrict__ w2, const float* __restrict__ root2,
    unsigned short* __restrict__ abf0,
    unsigned short* __restrict__ wt0, unsigned short* __restrict__ wt1,
    unsigned short* __restrict__ wt2, unsigned int* __restrict__ gmax) {
  int blk = blockIdx.x, tid = threadIdx.x;
  if (blk < 8192) {                        // convx: R*128 elements
    int idx = blk * 256 + tid;
    int row = idx >> 7, k = idx & 127;
    float v = x[idx];
    unsigned short hi = to_bf16_rne(v);
    unsigned short lo = to_bf16_rne(v - bf16_to_f(hi));
    size_t base = (size_t)row * 384;
    abf0[base + k] = hi;
    abf0[base + 128 + k] = lo;
    abf0[base + 256 + k] = hi;
  } else if (blk < 8512) {                 // packw0: 640*128
    packw_body(w0, root0, 128, wt0, (blk - 8192) * 256 + tid);
  } else if (blk < 8672) {                 // packw1: 640*64
    packw_body(w1, root1, 64, wt1, (blk - 8512) * 256 + tid);
  } else if (blk < 8832) {                 // packw2: 640*64
    packw_body(w2, root2, 64, wt2, (blk - 8672) * 256 + tid);
  } else {                                 // zerog: 2048
    int idx = (blk - 8832) * 256 + tid;
    if (idx < B_ * F_) gmax[idx] = 0u;
  }
}

// ---------------- split-bf16 MFMA GEMM -> bf16 hw + fp32 root ----------------
// 128x128 tile, 256 threads = 4 waves (2x2 of 64x64), 16x16x32 bf16 MFMA, BK=64.
// LDS rows padded +8 bf16 (stride 144B -> conflict-free b128 frag reads).
#define BK 64
#define LDK (BK + 8)
__global__ __launch_bounds__(256) void gemm_mfma_kernel(
    const unsigned short* __restrict__ A,   // [M][KP]
    const unsigned short* __restrict__ Wt,  // [640][KP]  (W^T, n-major)
    unsigned short* __restrict__ hwbf,      // [M][576] bf16
    float* __restrict__ hwroot,             // [M][64] fp32
    int KP) {
  __shared__ unsigned short As[128 * LDK];
  __shared__ unsigned short Ws[128 * LDK];
  int bm = blockIdx.x * 128;
  int bn = blockIdx.y * 128;
  int tid = threadIdx.x;
  int wave = tid >> 6, lane = tid & 63;
  int mw = (wave & 1) * 64, nw = (wave >> 1) * 64;
  int lr = lane & 15, quad = lane >> 4;

  f32x4 acc[4][4] = {};
  for (int k0 = 0; k0 < KP; k0 += BK) {
    #pragma unroll
    for (int i = 0; i < 4; ++i) {
      int c = tid + i * 256;            // 0..1023 chunks of 16B
      int row = c >> 3, ck = (c & 7) * 8;
      *(float4*)&As[row * LDK + ck] =
          *(const float4*)&A[(size_t)(bm + row) * KP + k0 + ck];
      *(float4*)&Ws[row * LDK + ck] =
          *(const float4*)&Wt[(size_t)(bn + row) * KP + k0 + ck];
    }
    __syncthreads();
    #pragma unroll
    for (int kk = 0; kk < BK; kk += 32) {
      bf16x8 af[4], bf[4];
      #pragma unroll
      for (int i = 0; i < 4; ++i)
        af[i] = *(const bf16x8*)&As[(mw + 16 * i + lr) * LDK + kk + quad * 8];
      #pragma unroll
      for (int j = 0; j < 4; ++j)
        bf[j] = *(const bf16x8*)&Ws[(nw + 16 * j + lr) * LDK + kk + quad * 8];
      #pragma unroll
      for (int i = 0; i < 4; ++i)
        #pragma unroll
        for (int j = 0; j < 4; ++j)
          acc[i][j] = __builtin_amdgcn_mfma_f32_16x16x32_bf16(af[i], bf[j], acc[i][j], 0, 0, 0);
    }
    __syncthreads();
  }
  // epilogue: C/D layout col=lane&15, row=quad*4+reg (m89-verified).
  int kku = (bn + nw) >> 6;
  if (kku < 9) {
    #pragma unroll
    for (int i = 0; i < 4; ++i)
      #pragma unroll
      for (int j = 0; j < 4; ++j)
        #pragma unroll
        for (int r = 0; r < 4; ++r) {
          int m = bm + mw + 16 * i + quad * 4 + r;
          int n = bn + nw + 16 * j + lr;            // 64*kku .. 64*kku+63
          hwbf[(size_t)m * HWC + n] = to_bf16_rne(acc[i][j][r]);
        }
  } else {
    #pragma unroll
    for (int i = 0; i < 4; ++i)
      #pragma unroll
      for (int j = 0; j < 4; ++j)
        #pragma unroll
        for (int r = 0; r < 4; ++r) {
          int m = bm + mw + 16 * i + quad * 4 + r;
          int f = 16 * j + lr;
          hwroot[(size_t)m * F_ + f] = acc[i][j][r];
        }
  }
}

// ---------------- sparse aggregate (bf16 taps, scalar base + ping-pong) ----------------
// 256 threads = 4 waves, one row per wave. XCD-swizzled (blockIdx&7 = XCD).
// Edge base -> SGPR via readfirstlane: taps are ushort loads with immediate
// offsets off a uniform base (+ lane f). 4-edge groups, explicit A/B prefetch.
__global__ __launch_bounds__(256) void aggregate_kernel(
    const unsigned short* __restrict__ hwbf,
    const float* __restrict__ hwroot,
    const float4* __restrict__ edge,
    const int* __restrict__ cnt, const float* __restrict__ deginv,
    const float* __restrict__ bias,
    unsigned short* __restrict__ aout,
    unsigned int* __restrict__ gmax) {
  __shared__ float4 esh[4][CAP];
  int wave = threadIdx.x >> 6;
  int f = threadIdx.x & 63;
  int xcd = blockIdx.x & 7;
  int j = blockIdx.x >> 3;
  int b = xcd * 4 + (j >> 7);
  int row = b * N_ + ((j & 127) << 2) + wave;
  int c = cnt[row];
  int cpad = (c + 3) & ~3;
  size_t ebase = (size_t)row * CAP;
  for (int i = f; i < cpad; i += 64)
    esh[wave][i] = (i < c) ? edge[ebase + i] : make_float4(0.f, 0.f, 0.f, 0.f);
  __syncthreads();

  const unsigned short* pb = hwbf + (size_t)b * (N_ * HWC);
  float accs[4] = {0.f, 0.f, 0.f, 0.f};

  auto load_group = [&](int g, unsigned short* t, float* wt) {
    #pragma unroll
    for (int q = 0; q < 4; ++q) {
      float4 er = esh[wave][g * 4 + q];
      int off = __builtin_amdgcn_readfirstlane(__float_as_int(er.x));
      const unsigned short* p = pb + off + f;   // uniform base + lane offset
      t[4 * q + 0] = p[0];
      t[4 * q + 1] = p[F_];
      t[4 * q + 2] = p[3 * F_];
      t[4 * q + 3] = p[4 * F_];
      float bx1 = er.y, by1 = er.z, v = er.w;
      float bx0 = v - bx1, by0 = v - by1;
      wt[4 * q + 0] = bx0 * by0; wt[4 * q + 1] = bx0 * by1;
      wt[4 * q + 2] = bx1 * by0; wt[4 * q + 3] = bx1 * by1;
    }
  };
  auto consume = [&](const unsigned short* t, const float* wt) {
    #pragma unroll
    for (int q = 0; q < 4; ++q)
      accs[q] += wt[4 * q + 0] * bf16_to_f(t[4 * q + 0])
               + wt[4 * q + 1] * bf16_to_f(t[4 * q + 1])
               + wt[4 * q + 2] * bf16_to_f(t[4 * q + 2])
               + wt[4 * q + 3] * bf16_to_f(t[4 * q + 3]);
  };

  int ng = cpad >> 2;
  unsigned short tA[16], tB[16];
  float wA[16], wB[16];
  if (ng > 0) load_group(0, tA, wA);
  int g = 0;
  for (; g + 2 <= ng; g += 2) {
    load_group(g + 1, tB, wB);     // prefetch B while A pending
    consume(tA, wA);
    if (g + 2 < ng) load_group(g + 2, tA, wA);  // prefetch A while B pending
    consume(tB, wB);
  }
  if (g < ng) consume(tA, wA);     // odd tail (already loaded)

  float di = deginv[row];
  float rootv = hwroot[(size_t)row * F_ + f];
  float val = fmaxf(((accs[0] + accs[1]) + (accs[2] + accs[3])) * di + rootv + bias[f], 0.0f);
  if (aout) {
    unsigned short hi = to_bf16_rne(val);
    unsigned short lo = to_bf16_rne(val - bf16_to_f(hi));
    size_t base = (size_t)row * 192;
    aout[base + f] = hi;
    aout[base + 64 + f] = lo;
    aout[base + 128 + f] = hi;
  }
  if (gmax) {
    // relu output >= 0 -> IEEE bits monotone under unsigned compare
    atomicMax(&gmax[b * F_ + f], __float_as_uint(val));
  }
}

// ---------------- FC from pooled features ----------------
__global__ __launch_bounds__(64) void fc_kernel(
    const float* __restrict__ g, const float* __restrict__ fcw,
    const float* __restrict__ fcb, float* __restrict__ out) {
  int b = blockIdx.x;
  int f = threadIdx.x;
  __shared__ float gs[64];
  gs[f] = g[b * F_ + f];
  __syncthreads();
  if (f < 10) {
    float s = fcb[f];
    #pragma unroll
    for (int c = 0; c < 64; ++c) s += gs[c] * fcw[c * 10 + f];
    out[b * 10 + f] = s;
  }
}

extern "C" void kernel_launch(void* const* d_in, const int* in_sizes, int n_in,
                              void* d_out, int out_size, void* d_ws, size_t ws_size,
                              hipStream_t stream) {
  const float* x     = (const float*)d_in[0];
  const float* coord = (const float*)d_in[1];
  const float* adj   = (const float*)d_in[2];
  const float* w0    = (const float*)d_in[3];
  const float* root0 = (const float*)d_in[4];
  const float* b0    = (const float*)d_in[5];
  const float* w1    = (const float*)d_in[6];
  const float* root1 = (const float*)d_in[7];
  const float* b1    = (const float*)d_in[8];
  const float* w2    = (const float*)d_in[9];
  const float* root2 = (const float*)d_in[10];
  const float* b2    = (const float*)d_in[11];
  const float* fcw   = (const float*)d_in[12];
  const float* fcb   = (const float*)d_in[13];
  float* out = (float*)d_out;

  char* ws = (char*)d_ws;
  size_t off = 0;
  auto alloc = [&](size_t bytes) {
    void* p = ws + off;
    off = (off + bytes + 255) & ~(size_t)255;
    return p;
  };
  const int R = B_ * N_;  // 16384
  float4* edge    = (float4*)alloc((size_t)R * CAP * 16);
  int*    cnt     = (int*)   alloc((size_t)R * 4);
  float*  deginv  = (float*) alloc((size_t)R * 4);
  unsigned short* abf0 = (unsigned short*)alloc((size_t)R * 384 * 2);
  unsigned short* abfN = (unsigned short*)alloc((size_t)R * 192 * 2);
  unsigned short* wt0  = (unsigned short*)alloc((size_t)NCOL * 384 * 2);
  unsigned short* wt1  = (unsigned short*)alloc((size_t)NCOL * 192 * 2);
  unsigned short* wt2  = (unsigned short*)alloc((size_t)NCOL * 192 * 2);
  unsigned short* hwbf = (unsigned short*)alloc((size_t)R * HWC * 2);
  float*  hwroot  = (float*) alloc((size_t)R * F_ * 4);
  unsigned int* gmax = (unsigned int*)alloc((size_t)B_ * F_ * 4);

  preprocess_kernel<<<R, 512, 0, stream>>>(adj, coord, edge, cnt, deginv);
  setup_kernel<<<8840, 256, 0, stream>>>(x, w0, root0, w1, root1, w2, root2,
                                         abf0, wt0, wt1, wt2, gmax);

  // layer 0 (Cin=128, KP=384)
  gemm_mfma_kernel<<<dim3(R / 128, NCOL / 128), 256, 0, stream>>>(abf0, wt0, hwbf, hwroot, 384);
  aggregate_kernel<<<R / 4, 256, 0, stream>>>(hwbf, hwroot, edge, cnt, deginv, b0, abfN, nullptr);

  // layer 1 (Cin=64, KP=192)
  gemm_mfma_kernel<<<dim3(R / 128, NCOL / 128), 256, 0, stream>>>(abfN, wt1, hwbf, hwroot, 192);
  aggregate_kernel<<<R / 4, 256, 0, stream>>>(hwbf, hwroot, edge, cnt, deginv, b1, abfN, nullptr);

  // layer 2 (Cin=64, KP=192) — fused max-pool
  gemm_mfma_kernel<<<dim3(R / 128, NCOL / 128), 256, 0, stream>>>(abfN, wt2, hwbf, hwroot, 192);
  aggregate_kernel<<<R / 4, 256, 0, stream>>>(hwbf, hwroot, edge, cnt, deginv, b2, nullptr, gmax);

  fc_kernel<<<B_, 64, 0, stream>>>((const float*)gmax, fcw, fcb, out);
}